// Round 5
// baseline (128.885 us; speedup 1.0000x reference)
//
#include <hip/hip_runtime.h>
#include <math.h>

// (T, B, D) = (1024, 16, 1024); C = B*D = 16384 independent column scans
// y[t] = beta * y[t-1] + x[t],  beta = sigmoid(beta_param)
//
// R5: decoupled two-half scan. 512 blocks of 512 threads (8 waves); block =
// 64 columns x 512 rows (half of T). 2 blocks resident per CU so read and
// store phases of different blocks overlap (R1's single 16-wave block had a
// full-CU barrier bubble between its load and store phases). Upper-half
// blocks obtain y[511] from lower-half blocks via device-scope atomics +
// flag poll (all 512 blocks co-resident at <=128 VGPR -> no deadlock).
// ws poison 0xAAAAAAAA != 1 acts as the "not ready" flag state.
#define T_DIM   1024
#define C_DIM   16384
#define HALF_T  512
#define WAVES   8
#define BLOCK_T 512
#define L_CHUNK 64            // rows per wave
#define NTILES  256           // C_DIM / 64 column tiles

__global__ __launch_bounds__(BLOCK_T, 4)
void pli_scan2(const float* __restrict__ x,
               const float* __restrict__ beta_p,
               float* __restrict__ out,
               float* __restrict__ ws_carry,   // [NTILES*64] y[511] per column
               int*   __restrict__ ws_flag) {  // [NTILES*32] flag per tile (128B stride)
    const int lane = threadIdx.x & 63;
    const int w    = threadIdx.x >> 6;            // wave id within half
    const int tile = blockIdx.x & (NTILES - 1);
    const int h    = blockIdx.x >> 8;             // 0 = rows 0..511, 1 = rows 512..1023
    const int col  = (tile << 6) + lane;

    const float beta = 1.0f / (1.0f + expf(-beta_p[0]));

    const int row0 = h * HALF_T + w * L_CHUNK;
    const size_t base = (size_t)row0 * C_DIM + col;
    const float* xp = x + base;

    // Stage 64 rows in registers (coalesced, plain loads — nt hurt in R3/R4)
    float v[L_CHUNK];
#pragma unroll
    for (int t = 0; t < L_CHUNK; ++t) v[t] = xp[(size_t)t * C_DIM];

    // Zero-initialized local scan
    float run = 0.0f;
#pragma unroll
    for (int t = 0; t < L_CHUNK; ++t) { run = fmaf(run, beta, v[t]); v[t] = run; }

    // Intra-block carry exchange
    __shared__ float carry[WAVES][64];
    carry[w][lane] = run;
    __syncthreads();

    float bL = beta;                              // beta^64
#pragma unroll
    for (int i = 0; i < 6; ++i) bL *= bL;

    // In-half prefix for this wave's chunk
    float Y = 0.0f;
    for (int u = 0; u < w; ++u) Y = fmaf(Y, bL, carry[u][lane]);

    if (h == 1) {
        // Look-back: wait for lower half's published y[511]
        if (threadIdx.x == 0) {
            while (atomicAdd(ws_flag + tile * 32, 0) != 1)
                __builtin_amdgcn_s_sleep(8);
        }
        __syncthreads();
        const float Y511 = atomicAdd(ws_carry + (tile << 6) + lane, 0.0f);
        float bLw = 1.0f;                         // beta^(64*w)
        for (int i = 0; i < w; ++i) bLw *= bL;
        Y = fmaf(Y511, bLw, Y);                   // true prefix at row row0-1
    }

    // y[row0+t] = local[t] + beta^(t+1) * Y
    float m = beta * Y;
    float* op = out + base;
    float lastv = 0.0f;
#pragma unroll
    for (int t = 0; t < L_CHUNK; ++t) {
        const float val = v[t] + m;
        op[(size_t)t * C_DIM] = val;
        m *= beta;
        lastv = val;                              // value at row row0+63
    }

    // Lower half, last wave: publish y[511] then raise the flag
    if (h == 0 && w == WAVES - 1) {
        atomicExch(ws_carry + (tile << 6) + lane, lastv);  // device-scope
        __threadfence();
        if (lane == 0) atomicExch(ws_flag + tile * 32, 1);
    }
}

extern "C" void kernel_launch(void* const* d_in, const int* in_sizes, int n_in,
                              void* d_out, int out_size, void* d_ws, size_t ws_size,
                              hipStream_t stream) {
    const float* x      = (const float*)d_in[0];   // [T, B, D] fp32
    const float* beta_p = (const float*)d_in[1];   // scalar fp32
    float* out          = (float*)d_out;

    float* ws_carry = (float*)d_ws;                           // 64 KiB
    int*   ws_flag  = (int*)((char*)d_ws + NTILES * 64 * 4);  // 32 KiB, 128B stride

    dim3 grid(2 * NTILES);     // 512 blocks: h=0 first, then h=1
    dim3 block(BLOCK_T);       // 512 threads = 8 waves
    hipLaunchKernelGGL(pli_scan2, grid, block, 0, stream,
                       x, beta_p, out, ws_carry, ws_flag);
}

// Round 6
// 121.326 us; speedup vs baseline: 1.0623x; 1.0623x over previous
//
#include <hip/hip_runtime.h>
#include <math.h>

// (T, B, D) = (1024, 16, 1024); C = B*D = 16384 independent column scans
// y[t] = beta * y[t-1] + x[t],  beta = sigmoid(beta_param)
//
// R6: same single-pass register scan as R1 (one read + one write per element,
// 134 MB = traffic floor) but block = 32 columns x full T with 512 threads,
// giving 512 blocks -> 2 co-resident blocks per CU. The two blocks' internal
// load->barrier->store phases interleave, overlapping read and write streams
// on every CU (R1 had one 16-wave block per CU: full drain at the barrier).
// No cross-block dependency (R5's look-back serialization is gone).
// Per wave instruction: 2 x 128 B segments = 2 cache lines, same as R1's
// 1 x 256 B. Plain loads/stores (nt hurt in R3/R4).
#define T_DIM   1024
#define C_DIM   16384
#define COLS    32            // columns per block
#define SEGS    16            // row segments per column
#define SEG_ROWS 64           // rows per segment (= registers per thread)
#define BLOCK_T 512           // 8 waves

__global__ __launch_bounds__(BLOCK_T, 4)
void pli_scan3(const float* __restrict__ x,
               const float* __restrict__ beta_p,
               float* __restrict__ out) {
    const int c   = threadIdx.x & (COLS - 1);     // column within tile
    const int s   = threadIdx.x >> 5;             // row-segment id [0,16)
    const int col = blockIdx.x * COLS + c;

    const float beta = 1.0f / (1.0f + expf(-beta_p[0]));

    const size_t base = (size_t)(s * SEG_ROWS) * C_DIM + col;
    const float* xp = x + base;

    // Stage 64 rows of this column in registers
    float v[SEG_ROWS];
#pragma unroll
    for (int t = 0; t < SEG_ROWS; ++t) v[t] = xp[(size_t)t * C_DIM];

    // Zero-initialized local scan
    float run = 0.0f;
#pragma unroll
    for (int t = 0; t < SEG_ROWS; ++t) { run = fmaf(run, beta, v[t]); v[t] = run; }

    // Segment-carry exchange (16 segments x 32 cols; reads broadcast across
    // the two half-waves -> no bank conflicts)
    __shared__ float carry[SEGS][COLS];
    carry[s][c] = run;
    __syncthreads();

    // beta^64 via repeated squaring
    float bL = beta;
#pragma unroll
    for (int i = 0; i < 6; ++i) bL *= bL;

    // Prefix at the row before this segment: Y = sum_{u<s} bL^(s-1-u) carry[u]
    // (trip count differs by 1 across half-waves -> negligible divergence)
    float Y = 0.0f;
    for (int u = 0; u < s; ++u) Y = fmaf(Y, bL, carry[u][c]);

    // y[row0+t] = local[t] + beta^(t+1) * Y
    float m = beta * Y;
    float* op = out + base;
#pragma unroll
    for (int t = 0; t < SEG_ROWS; ++t) {
        op[(size_t)t * C_DIM] = v[t] + m;
        m *= beta;
    }
}

extern "C" void kernel_launch(void* const* d_in, const int* in_sizes, int n_in,
                              void* d_out, int out_size, void* d_ws, size_t ws_size,
                              hipStream_t stream) {
    const float* x      = (const float*)d_in[0];   // [T, B, D] fp32
    const float* beta_p = (const float*)d_in[1];   // scalar fp32
    float* out          = (float*)d_out;

    dim3 grid(C_DIM / COLS);   // 512 blocks -> 2 per CU
    dim3 block(BLOCK_T);       // 512 threads = 8 waves
    hipLaunchKernelGGL(pli_scan3, grid, block, 0, stream, x, beta_p, out);
}